// Round 1
// baseline (3006.514 us; speedup 1.0000x reference)
//
#include <hip/hip_runtime.h>

#define NN 100000
#define NE 1600000
#define HD 128

// out[n][c] = bias[c] + sum_k in[n][k] * Wg[cbase+c][k]   (c in [0,CT))
// Optionally relu the staged input and write it back (for the pred head,
// which must also emit x_new = relu(agg + phi(u)) as an output).
template<int CT, int LDO, bool RELU_WB>
__global__ __launch_bounds__(256) void gemm_nodes(
    const float* __restrict__ in,
    float* in_wb,                       // == in when RELU_WB (no restrict: aliases)
    const float* __restrict__ Wg,      // [C_total, 128] row-major
    const float* __restrict__ bias,
    float* __restrict__ out)
{
  __shared__ float Wt[HD * CT];        // transposed W, float2-chunk XOR swizzle
  __shared__ float xs[32 * HD];
  const int tid = threadIdx.x;
  const int cbase = blockIdx.y * CT;

  // Stage W transposed: Wt[k][c]. Swizzle the float2 chunk index by k to
  // avoid the 64-way bank conflict a raw transpose write would have.
  for (int idx = tid; idx < HD * CT; idx += 256) {
    int c = idx >> 7, k = idx & 127;                 // coalesced global read
    int chunk = ((c >> 1) ^ (k & 31));
    Wt[k * CT + (chunk << 1 | (c & 1))] = Wg[(size_t)(cbase + c) * HD + k];
  }
  const long nb = (long)blockIdx.x * 32;
  for (int idx = tid; idx < 32 * HD; idx += 256) {
    int n = idx >> 7, k = idx & 127;
    float v = in[(nb + n) * HD + k];
    if (RELU_WB) { v = fmaxf(v, 0.0f); in_wb[(nb + n) * HD + k] = v; }
    xs[idx] = v;
  }
  __syncthreads();

  const int lane = tid & 31;
  const int grp  = tid >> 5;            // 8 groups x 4 nodes = 32 nodes/block
  const int c0   = lane * 2;            // 2 consecutive channels per lane

  float acc[4][2];
#pragma unroll
  for (int j = 0; j < 4; j++) {
    acc[j][0] = bias[cbase + c0];
    acc[j][1] = bias[cbase + c0 + 1];
  }

#pragma unroll 4
  for (int k = 0; k < HD; k += 4) {
    float xv[4][4];
#pragma unroll
    for (int j = 0; j < 4; j++) {       // broadcast reads (same addr per group)
      float4 t = *(const float4*)&xs[(grp * 4 + j) * HD + k];
      xv[j][0] = t.x; xv[j][1] = t.y; xv[j][2] = t.z; xv[j][3] = t.w;
    }
#pragma unroll
    for (int kk = 0; kk < 4; kk++) {
      int chunk = lane ^ ((k + kk) & 31);
      float2 w = *(const float2*)&Wt[(k + kk) * CT + (chunk << 1)];
#pragma unroll
      for (int j = 0; j < 4; j++) {
        acc[j][0] = fmaf(xv[j][kk], w.x, acc[j][0]);
        acc[j][1] = fmaf(xv[j][kk], w.y, acc[j][1]);
      }
    }
  }
#pragma unroll
  for (int j = 0; j < 4; j++) {
    long n = nb + grp * 4 + j;
    *(float2*)&out[n * LDO + cbase + c0] = make_float2(acc[j][0], acc[j][1]);
  }
}

// 32 lanes per edge, float4 per lane: gather h[src] row, atomic-add into agg[tgt].
__global__ __launch_bounds__(256) void scatter_edges(
    const int* __restrict__ ei,
    const float* __restrict__ h,
    float* __restrict__ agg)
{
  const long t = (long)blockIdx.x * 256 + threadIdx.x;
  const int e = (int)(t >> 5);
  const int lane = (int)(t & 31);
  const int src = ei[e];
  const int tgt = ei[NE + e];
  const float4 v = *(const float4*)&h[(size_t)src * HD + lane * 4];
  float* dst = &agg[(size_t)tgt * HD + lane * 4];
  unsafeAtomicAdd(dst + 0, v.x);
  unsafeAtomicAdd(dst + 1, v.y);
  unsafeAtomicAdd(dst + 2, v.z);
  unsafeAtomicAdd(dst + 3, v.w);
}

extern "C" void kernel_launch(void* const* d_in, const int* in_sizes, int n_in,
                              void* d_out, int out_size, void* d_ws, size_t ws_size,
                              hipStream_t stream) {
  const float* x      = (const float*)d_in[0];
  const float* u      = (const float*)d_in[1];
  const int*   ei     = (const int*)d_in[2];
  const float* W_w    = (const float*)d_in[3];
  const float* W_b    = (const float*)d_in[4];
  const float* phi_w  = (const float*)d_in[5];
  const float* phi_b  = (const float*)d_in[6];
  const float* pred_w = (const float*)d_in[7];
  const float* pred_b = (const float*)d_in[8];

  float* out_x = (float*)d_out;                     // [NN,128] = x_new
  float* out_y = (float*)d_out + (size_t)NN * HD;   // [NN,64]  = y
  float* h     = (float*)d_ws;                      // [NN,128] scratch

  dim3 blk(256);
  // K1: h = x @ W_w^T + W_b
  gemm_nodes<64, 128, false><<<dim3(NN / 32, 2), blk, 0, stream>>>(
      x, nullptr, W_w, W_b, h);
  // K2: out_x = u @ phi_w^T + phi_b   (scatter accumulates on top)
  gemm_nodes<64, 128, false><<<dim3(NN / 32, 2), blk, 0, stream>>>(
      u, nullptr, phi_w, phi_b, out_x);
  // K3: out_x += segment_sum(h[src]) at tgt
  scatter_edges<<<dim3((NE * 32) / 256), blk, 0, stream>>>(ei, h, out_x);
  // K4: out_x = relu(out_x) in place; out_y = out_x @ pred_w^T + pred_b
  gemm_nodes<64, 64, true><<<dim3(NN / 32, 1), blk, 0, stream>>>(
      out_x, out_x, pred_w, pred_b, out_y);
}

// Round 2
// 560.588 us; speedup vs baseline: 5.3631x; 5.3631x over previous
//
#include <hip/hip_runtime.h>

#define NN 100000
#define NE 1600000
#define HD 128
#define CAP 64   // per-node edge-list capacity; deg ~ Poisson(16), P(>64) ~ 1e-18

// out[n][c] = bias[c] + sum_k in[n][k] * Wg[cbase+c][k]   (c in [0,CT))
template<int CT, int LDO, bool RELU_WB>
__global__ __launch_bounds__(256) void gemm_nodes(
    const float* __restrict__ in,
    float* in_wb,                       // == in when RELU_WB (aliases)
    const float* __restrict__ Wg,      // [C_total, 128] row-major
    const float* __restrict__ bias,
    float* __restrict__ out)
{
  __shared__ float Wt[HD * CT];        // transposed W, float2-chunk XOR swizzle
  __shared__ float xs[32 * HD];
  const int tid = threadIdx.x;
  const int cbase = blockIdx.y * CT;

  for (int idx = tid; idx < HD * CT; idx += 256) {
    int c = idx >> 7, k = idx & 127;                 // coalesced global read
    int chunk = ((c >> 1) ^ (k & 31));
    Wt[k * CT + (chunk << 1 | (c & 1))] = Wg[(size_t)(cbase + c) * HD + k];
  }
  const long nb = (long)blockIdx.x * 32;
  for (int idx = tid; idx < 32 * HD; idx += 256) {
    int n = idx >> 7, k = idx & 127;
    float v = in[(nb + n) * HD + k];
    if (RELU_WB) { v = fmaxf(v, 0.0f); in_wb[(nb + n) * HD + k] = v; }
    xs[idx] = v;
  }
  __syncthreads();

  const int lane = tid & 31;
  const int grp  = tid >> 5;            // 8 groups x 4 nodes = 32 nodes/block
  const int c0   = lane * 2;

  float acc[4][2];
#pragma unroll
  for (int j = 0; j < 4; j++) {
    acc[j][0] = bias[cbase + c0];
    acc[j][1] = bias[cbase + c0 + 1];
  }

#pragma unroll 4
  for (int k = 0; k < HD; k += 4) {
    float xv[4][4];
#pragma unroll
    for (int j = 0; j < 4; j++) {
      float4 t = *(const float4*)&xs[(grp * 4 + j) * HD + k];
      xv[j][0] = t.x; xv[j][1] = t.y; xv[j][2] = t.z; xv[j][3] = t.w;
    }
#pragma unroll
    for (int kk = 0; kk < 4; kk++) {
      int chunk = lane ^ ((k + kk) & 31);
      float2 w = *(const float2*)&Wt[(k + kk) * CT + (chunk << 1)];
#pragma unroll
      for (int j = 0; j < 4; j++) {
        acc[j][0] = fmaf(xv[j][kk], w.x, acc[j][0]);
        acc[j][1] = fmaf(xv[j][kk], w.y, acc[j][1]);
      }
    }
  }
#pragma unroll
  for (int j = 0; j < 4; j++) {
    long n = nb + grp * 4 + j;
    *(float2*)&out[n * LDO + cbase + c0] = make_float2(acc[j][0], acc[j][1]);
  }
}

__global__ __launch_bounds__(256) void zero_cur(int* __restrict__ cur) {
  int i = blockIdx.x * 256 + threadIdx.x;
  if (i < NN) cur[i] = 0;
}

// One thread per edge: append src to tgt's list. Int atomics only.
__global__ __launch_bounds__(256) void bucket_edges(
    const int* __restrict__ ei,
    int* __restrict__ cur,
    int* __restrict__ list,
    const float* __restrict__ h,
    float* out_x)                        // fallback target (overflow only)
{
  const long t = (long)blockIdx.x * 256 + threadIdx.x;
  if (t >= NE) return;
  const int src = ei[t];
  const int tgt = ei[NE + t];
  const int pos = atomicAdd(&cur[tgt], 1);
  if (pos < CAP) {
    list[(size_t)tgt * CAP + pos] = src;
  } else {
    // essentially-never overflow path: direct float atomics (h already built)
    for (int c = 0; c < HD; c++)
      unsafeAtomicAdd(&out_x[(size_t)tgt * HD + c], h[(size_t)src * HD + c]);
  }
}

// One wave per node: acc = phi_u (already in out_x) + sum over edges of h[src];
// apply relu, write x_new.
__global__ __launch_bounds__(256) void gather_nodes(
    const int* __restrict__ cur,
    const int* __restrict__ list,
    const float* __restrict__ h,
    float* __restrict__ xout)
{
  const int wave = threadIdx.x >> 6;
  const int lane = threadIdx.x & 63;
  const long n = (long)blockIdx.x * 4 + wave;
  if (n >= NN) return;
  int deg = cur[n];
  if (deg > CAP) deg = CAP;
  const int my = (lane < deg) ? list[n * CAP + lane] : 0;

  float2 acc = *(const float2*)&xout[n * HD + lane * 2];
  for (int e = 0; e < deg; e++) {
    const int s = __shfl(my, e, 64);
    const float2 v = *(const float2*)&h[(size_t)s * HD + lane * 2];
    acc.x += v.x;
    acc.y += v.y;
  }
  acc.x = fmaxf(acc.x, 0.0f);
  acc.y = fmaxf(acc.y, 0.0f);
  *(float2*)&xout[n * HD + lane * 2] = acc;
}

// Round-1 fallback (used only if ws_size is too small for the CSR path).
__global__ __launch_bounds__(256) void scatter_edges(
    const int* __restrict__ ei,
    const float* __restrict__ h,
    float* __restrict__ agg)
{
  const long t = (long)blockIdx.x * 256 + threadIdx.x;
  const int e = (int)(t >> 5);
  const int lane = (int)(t & 31);
  const int src = ei[e];
  const int tgt = ei[NE + e];
  const float4 v = *(const float4*)&h[(size_t)src * HD + lane * 4];
  float* dst = &agg[(size_t)tgt * HD + lane * 4];
  unsafeAtomicAdd(dst + 0, v.x);
  unsafeAtomicAdd(dst + 1, v.y);
  unsafeAtomicAdd(dst + 2, v.z);
  unsafeAtomicAdd(dst + 3, v.w);
}

extern "C" void kernel_launch(void* const* d_in, const int* in_sizes, int n_in,
                              void* d_out, int out_size, void* d_ws, size_t ws_size,
                              hipStream_t stream) {
  const float* x      = (const float*)d_in[0];
  const float* u      = (const float*)d_in[1];
  const int*   ei     = (const int*)d_in[2];
  const float* W_w    = (const float*)d_in[3];
  const float* W_b    = (const float*)d_in[4];
  const float* phi_w  = (const float*)d_in[5];
  const float* phi_b  = (const float*)d_in[6];
  const float* pred_w = (const float*)d_in[7];
  const float* pred_b = (const float*)d_in[8];

  float* out_x = (float*)d_out;                     // [NN,128] = x_new
  float* out_y = (float*)d_out + (size_t)NN * HD;   // [NN,64]  = y

  float* h   = (float*)d_ws;                        // [NN,128]
  int*  cur  = (int*)(h + (size_t)NN * HD);         // [NN]
  int*  list = cur + ((NN + 63) & ~63);             // [NN, CAP]
  const size_t need = (size_t)NN * HD * 4 + ((NN + 63) & ~63) * 4
                    + (size_t)NN * CAP * 4;

  dim3 blk(256);
  // K1: h = x @ W_w^T + W_b
  gemm_nodes<64, 128, false><<<dim3(NN / 32, 2), blk, 0, stream>>>(
      x, nullptr, W_w, W_b, h);
  // K2: out_x = u @ phi_w^T + phi_b
  gemm_nodes<64, 128, false><<<dim3(NN / 32, 2), blk, 0, stream>>>(
      u, nullptr, phi_w, phi_b, out_x);

  if (ws_size >= need) {
    zero_cur<<<dim3((NN + 255) / 256), blk, 0, stream>>>(cur);
    bucket_edges<<<dim3((NE + 255) / 256), blk, 0, stream>>>(ei, cur, list, h, out_x);
    gather_nodes<<<dim3(NN / 4), blk, 0, stream>>>(cur, list, h, out_x);
    // K4: out_y = x_new @ pred_w^T + pred_b  (x_new already relu'd in out_x)
    gemm_nodes<64, 64, false><<<dim3(NN / 32, 1), blk, 0, stream>>>(
        out_x, nullptr, pred_w, pred_b, out_y);
  } else {
    scatter_edges<<<dim3((NE * 32) / 256), blk, 0, stream>>>(ei, h, out_x);
    gemm_nodes<64, 64, true><<<dim3(NN / 32, 1), blk, 0, stream>>>(
        out_x, out_x, pred_w, pred_b, out_y);
  }
}

// Round 3
// 402.578 us; speedup vs baseline: 7.4682x; 1.3925x over previous
//
#include <hip/hip_runtime.h>

#define NN 100000
#define NE 1600000
#define HD 128
#define CAP 64   // per-node edge-list capacity; deg ~ Poisson(16), P(>64) ~ 1e-18

typedef __attribute__((ext_vector_type(8))) short short8;   // 8 bf16 (4 VGPRs)
typedef __attribute__((ext_vector_type(4))) float v4f;      // MFMA acc

// ---- helpers ----------------------------------------------------------------
__device__ inline unsigned pk2(float a, float b) {          // 2x f32 -> packed bf16 (RNE)
  unsigned ua = __float_as_uint(a), ub = __float_as_uint(b);
  ua = (ua + 0x7fffu + ((ua >> 16) & 1u)) >> 16;
  ub = (ub + 0x7fffu + ((ub >> 16) & 1u)) >> 16;
  return ua | (ub << 16);
}

// ---- fp32 -> bf16 bulk convert (8 elems/thread) -----------------------------
__global__ __launch_bounds__(256) void cvt_bf16(
    const float* __restrict__ src, unsigned short* __restrict__ dst, int n8)
{
  int i = blockIdx.x * 256 + threadIdx.x;
  if (i >= n8) return;
  const float4* s = (const float4*)src + (size_t)i * 2;
  float4 a = s[0], b = s[1];
  uint4 o;
  o.x = pk2(a.x, a.y); o.y = pk2(a.z, a.w);
  o.z = pk2(b.x, b.y); o.w = pk2(b.z, b.w);
  ((uint4*)dst)[i] = o;
}

// ---- bf16 MFMA GEMM: out[n][c] = bias[c] + sum_k in[n][k]*W[c][k] -----------
// Transposed MFMA: A = W (M=channels), B = x (N=nodes). D: col=lane&15 (node),
// row=(lane>>4)*4+reg (channel) -> each lane holds 4 consecutive channels.
// Block = 4 waves, 32 nodes/wave = 128 nodes/block. No LDS.
template<int NCT, bool OUT_BF16>
__global__ __launch_bounds__(256) void gemm_mfma(
    const unsigned short* __restrict__ xb,   // [NN][128] bf16
    const unsigned short* __restrict__ wb,   // [NCT*16][128] bf16
    const float* __restrict__ bias,          // [NCT*16]
    void* __restrict__ outp)                 // [NN][NCT*16] bf16 or f32
{
  const int lane = threadIdx.x & 63;
  const int wv   = threadIdx.x >> 6;
  const long n0  = (long)blockIdx.x * 128 + wv * 32;
  const int r = lane & 15, hi = lane >> 4;

  // x fragments: 2 node-tiles x 4 k-steps, 8 k-contiguous bf16 per lane
  short8 xf[2][4];
#pragma unroll
  for (int nt = 0; nt < 2; nt++) {
    long n = n0 + nt * 16 + r;
    if (n >= NN) n = 0;                       // tail clamp (stores masked below)
    const unsigned short* row = xb + n * HD + hi * 8;
#pragma unroll
    for (int ks = 0; ks < 4; ks++)
      xf[nt][ks] = *(const short8*)(row + ks * 32);
  }

#pragma unroll
  for (int ct = 0; ct < NCT; ct++) {
    float4 bv = *(const float4*)&bias[ct * 16 + hi * 4];
    v4f aa[2];
    aa[0] = (v4f){bv.x, bv.y, bv.z, bv.w};
    aa[1] = aa[0];
    const unsigned short* wrow = wb + (size_t)(ct * 16 + r) * HD + hi * 8;
#pragma unroll
    for (int ks = 0; ks < 4; ks++) {
      short8 wf = *(const short8*)(wrow + ks * 32);
      aa[0] = __builtin_amdgcn_mfma_f32_16x16x32_bf16(wf, xf[0][ks], aa[0], 0, 0, 0);
      aa[1] = __builtin_amdgcn_mfma_f32_16x16x32_bf16(wf, xf[1][ks], aa[1], 0, 0, 0);
    }
#pragma unroll
    for (int nt = 0; nt < 2; nt++) {
      long n = n0 + nt * 16 + r;
      if (n < NN) {
        if (OUT_BF16) {
          unsigned short* o = (unsigned short*)outp + n * (NCT * 16) + ct * 16 + hi * 4;
          uint2 pv; pv.x = pk2(aa[nt][0], aa[nt][1]); pv.y = pk2(aa[nt][2], aa[nt][3]);
          *(uint2*)o = pv;
        } else {
          float* o = (float*)outp + n * (NCT * 16) + ct * 16 + hi * 4;
          *(float4*)o = make_float4(aa[nt][0], aa[nt][1], aa[nt][2], aa[nt][3]);
        }
      }
    }
  }
}

// ---- CSR build --------------------------------------------------------------
__global__ __launch_bounds__(256) void zero_cur(int* __restrict__ cur) {
  int i = blockIdx.x * 256 + threadIdx.x;
  if (i < NN) cur[i] = 0;
}

__global__ __launch_bounds__(256) void bucket_edges(
    const int* __restrict__ ei,
    int* __restrict__ cur,
    int* __restrict__ list,
    const unsigned short* __restrict__ hb,   // bf16 h (overflow path only)
    float* out_x)
{
  const long t = (long)blockIdx.x * 256 + threadIdx.x;
  if (t >= NE) return;
  const int src = ei[t];
  const int tgt = ei[NE + t];
  const int pos = atomicAdd(&cur[tgt], 1);
  if (pos < CAP) {
    list[(size_t)tgt * CAP + pos] = src;
  } else {                                   // essentially-never overflow path
    for (int c = 0; c < HD; c += 2) {
      unsigned hv = *(const unsigned*)&hb[(size_t)src * HD + c];
      unsafeAtomicAdd(&out_x[(size_t)tgt * HD + c],     __uint_as_float(hv << 16));
      unsafeAtomicAdd(&out_x[(size_t)tgt * HD + c + 1], __uint_as_float(hv & 0xffff0000u));
    }
  }
}

// ---- gather: out_x = relu(out_x + sum h[src]); also emit bf16 x_new ---------
__global__ __launch_bounds__(256) void gather_nodes(
    const int* __restrict__ cur,
    const int* __restrict__ list,
    const unsigned short* __restrict__ hb,
    float* __restrict__ xout,
    unsigned* __restrict__ xnb)              // [NN][64] packed bf16 pairs
{
  const int wave = threadIdx.x >> 6;
  const int lane = threadIdx.x & 63;
  const long n = (long)blockIdx.x * 4 + wave;
  if (n >= NN) return;
  int deg = cur[n];
  if (deg > CAP) deg = CAP;
  const int my = (lane < deg) ? list[n * CAP + lane] : 0;

  float2 acc = *(const float2*)&xout[n * HD + lane * 2];
  int e = 0;
  for (; e + 2 <= deg; e += 2) {
    const int s0 = __shfl(my, e, 64);
    const int s1 = __shfl(my, e + 1, 64);
    unsigned h0 = *(const unsigned*)&hb[(size_t)s0 * HD + lane * 2];
    unsigned h1 = *(const unsigned*)&hb[(size_t)s1 * HD + lane * 2];
    acc.x += __uint_as_float(h0 << 16);
    acc.y += __uint_as_float(h0 & 0xffff0000u);
    acc.x += __uint_as_float(h1 << 16);
    acc.y += __uint_as_float(h1 & 0xffff0000u);
  }
  if (e < deg) {
    const int s0 = __shfl(my, e, 64);
    unsigned h0 = *(const unsigned*)&hb[(size_t)s0 * HD + lane * 2];
    acc.x += __uint_as_float(h0 << 16);
    acc.y += __uint_as_float(h0 & 0xffff0000u);
  }
  acc.x = fmaxf(acc.x, 0.0f);
  acc.y = fmaxf(acc.y, 0.0f);
  *(float2*)&xout[n * HD + lane * 2] = acc;
  xnb[n * 64 + lane] = pk2(acc.x, acc.y);
}

// ---- fp32 fallback path (only if ws is too small for the bf16 path) ---------
template<int CT, int LDO, bool RELU_WB>
__global__ __launch_bounds__(256) void gemm_nodes(
    const float* __restrict__ in, float* in_wb,
    const float* __restrict__ Wg, const float* __restrict__ bias,
    float* __restrict__ out)
{
  __shared__ float Wt[HD * CT];
  __shared__ float xs[32 * HD];
  const int tid = threadIdx.x;
  const int cbase = blockIdx.y * CT;
  for (int idx = tid; idx < HD * CT; idx += 256) {
    int c = idx >> 7, k = idx & 127;
    int chunk = ((c >> 1) ^ (k & 31));
    Wt[k * CT + (chunk << 1 | (c & 1))] = Wg[(size_t)(cbase + c) * HD + k];
  }
  const long nb = (long)blockIdx.x * 32;
  for (int idx = tid; idx < 32 * HD; idx += 256) {
    int n = idx >> 7, k = idx & 127;
    float v = in[(nb + n) * HD + k];
    if (RELU_WB) { v = fmaxf(v, 0.0f); in_wb[(nb + n) * HD + k] = v; }
    xs[idx] = v;
  }
  __syncthreads();
  const int lane = tid & 31, grp = tid >> 5, c0 = lane * 2;
  float acc[4][2];
#pragma unroll
  for (int j = 0; j < 4; j++) { acc[j][0] = bias[cbase + c0]; acc[j][1] = bias[cbase + c0 + 1]; }
#pragma unroll 4
  for (int k = 0; k < HD; k += 4) {
    float xv[4][4];
#pragma unroll
    for (int j = 0; j < 4; j++) {
      float4 t = *(const float4*)&xs[(grp * 4 + j) * HD + k];
      xv[j][0] = t.x; xv[j][1] = t.y; xv[j][2] = t.z; xv[j][3] = t.w;
    }
#pragma unroll
    for (int kk = 0; kk < 4; kk++) {
      int chunk = lane ^ ((k + kk) & 31);
      float2 w = *(const float2*)&Wt[(k + kk) * CT + (chunk << 1)];
#pragma unroll
      for (int j = 0; j < 4; j++) {
        acc[j][0] = fmaf(xv[j][kk], w.x, acc[j][0]);
        acc[j][1] = fmaf(xv[j][kk], w.y, acc[j][1]);
      }
    }
  }
#pragma unroll
  for (int j = 0; j < 4; j++) {
    long n = nb + grp * 4 + j;
    *(float2*)&out[n * LDO + cbase + c0] = make_float2(acc[j][0], acc[j][1]);
  }
}

__global__ __launch_bounds__(256) void scatter_edges(
    const int* __restrict__ ei, const float* __restrict__ h, float* __restrict__ agg)
{
  const long t = (long)blockIdx.x * 256 + threadIdx.x;
  const int e = (int)(t >> 5), lane = (int)(t & 31);
  const int src = ei[e], tgt = ei[NE + e];
  const float4 v = *(const float4*)&h[(size_t)src * HD + lane * 4];
  float* dst = &agg[(size_t)tgt * HD + lane * 4];
  unsafeAtomicAdd(dst + 0, v.x); unsafeAtomicAdd(dst + 1, v.y);
  unsafeAtomicAdd(dst + 2, v.z); unsafeAtomicAdd(dst + 3, v.w);
}

// ---- launch -----------------------------------------------------------------
extern "C" void kernel_launch(void* const* d_in, const int* in_sizes, int n_in,
                              void* d_out, int out_size, void* d_ws, size_t ws_size,
                              hipStream_t stream) {
  const float* x      = (const float*)d_in[0];
  const float* u      = (const float*)d_in[1];
  const int*   ei     = (const int*)d_in[2];
  const float* W_w    = (const float*)d_in[3];
  const float* W_b    = (const float*)d_in[4];
  const float* phi_w  = (const float*)d_in[5];
  const float* phi_b  = (const float*)d_in[6];
  const float* pred_w = (const float*)d_in[7];
  const float* pred_b = (const float*)d_in[8];

  float* out_x = (float*)d_out;                       // [NN,128] x_new (f32)
  float* out_y = (float*)d_out + (size_t)NN * HD;     // [NN,64]  y (f32)

  const size_t NNHD = (size_t)NN * HD;                // 12.8M elems
  unsigned short* xb    = (unsigned short*)d_ws;      // [NN][128] bf16 (dies after K1 -> list reuses)
  unsigned short* hb    = xb + NNHD;                  // [NN][128] bf16 h
  unsigned short* ubxnb = hb + NNHD;                  // ub, then reused as x_new bf16
  unsigned short* Wb    = ubxnb + NNHD;               // 16K
  unsigned short* phib  = Wb + 16384;                 // 16K
  unsigned short* predb = phib + 16384;               // 8K
  int* cur  = (int*)(predb + 8192);                   // [NN]
  int* list = (int*)xb;                               // [NN][CAP] overlays xb
  const size_t need = (size_t)(3 * NNHD + 40960) * 2 + (size_t)NN * 4;

  dim3 blk(256);
  if (ws_size >= need) {
    // 0) bf16 conversions
    cvt_bf16<<<dim3((int)(NNHD / 8 + 255) / 256), blk, 0, stream>>>(x, xb, (int)(NNHD / 8));
    cvt_bf16<<<dim3((int)(NNHD / 8 + 255) / 256), blk, 0, stream>>>(u, ubxnb, (int)(NNHD / 8));
    cvt_bf16<<<dim3(8), blk, 0, stream>>>(W_w, Wb, 2048);
    cvt_bf16<<<dim3(8), blk, 0, stream>>>(phi_w, phib, 2048);
    cvt_bf16<<<dim3(4), blk, 0, stream>>>(pred_w, predb, 1024);
    // 1) h = x @ W_w^T + W_b  (bf16 out)
    gemm_mfma<8, true><<<dim3((NN + 127) / 128), blk, 0, stream>>>(xb, Wb, W_b, hb);
    // 2) out_x = u @ phi_w^T + phi_b  (f32 out)
    gemm_mfma<8, false><<<dim3((NN + 127) / 128), blk, 0, stream>>>(ubxnb, phib, phi_b, out_x);
    // 3) CSR build (list overlays dead xb)
    zero_cur<<<dim3((NN + 255) / 256), blk, 0, stream>>>(cur);
    bucket_edges<<<dim3((NE + 255) / 256), blk, 0, stream>>>(ei, cur, list, hb, out_x);
    // 4) gather + relu; emit bf16 x_new into ubxnb
    gather_nodes<<<dim3(NN / 4), blk, 0, stream>>>(cur, list, hb, out_x, (unsigned*)ubxnb);
    // 5) y = x_new @ pred_w^T + pred_b
    gemm_mfma<4, false><<<dim3((NN + 127) / 128), blk, 0, stream>>>(ubxnb, predb, pred_b, out_y);
  } else {
    // fp32 fallback (atomic scatter) — needs only h[NN][128] f32 in ws
    float* h = (float*)d_ws;
    gemm_nodes<64, 128, false><<<dim3(NN / 32, 2), blk, 0, stream>>>(x, nullptr, W_w, W_b, h);
    gemm_nodes<64, 128, false><<<dim3(NN / 32, 2), blk, 0, stream>>>(u, nullptr, phi_w, phi_b, out_x);
    scatter_edges<<<dim3((NE * 32) / 256), blk, 0, stream>>>(ei, h, out_x);
    gemm_nodes<64, 64, true><<<dim3(NN / 32, 1), blk, 0, stream>>>(out_x, out_x, pred_w, pred_b, out_y);
  }
}

// Round 4
// 375.435 us; speedup vs baseline: 8.0081x; 1.0723x over previous
//
#include <hip/hip_runtime.h>

#define NN 100000
#define NE 1600000
#define HD 128
#define NB 391          // buckets of 256 target nodes (tgt>>8), 391*256 >= 100000
#define CAP 64          // per-node LDS list capacity; deg~Poisson(16)
#define EPB 4096        // edges per histogram/partition block

typedef __attribute__((ext_vector_type(8))) short short8;   // 8 bf16
typedef __attribute__((ext_vector_type(4))) float v4f;
union U8 { uint4 u; short8 s; };

__device__ inline unsigned pk2(float a, float b) {          // 2x f32 -> packed bf16 (RNE)
  unsigned ua = __float_as_uint(a), ub = __float_as_uint(b);
  ua = (ua + 0x7fffu + ((ua >> 16) & 1u)) >> 16;
  ub = (ub + 0x7fffu + ((ub >> 16) & 1u)) >> 16;
  return ua | (ub << 16);
}
__device__ inline float blo(unsigned h) { return __uint_as_float(h << 16); }
__device__ inline float bhi(unsigned h) { return __uint_as_float(h & 0xffff0000u); }

// ---- fp32 -> bf16 bulk convert (8 elems/thread) -----------------------------
__global__ __launch_bounds__(256) void cvt_bf16(
    const float* __restrict__ src, unsigned short* __restrict__ dst, int n8)
{
  int i = blockIdx.x * 256 + threadIdx.x;
  if (i >= n8) return;
  const float4* s = (const float4*)src + (size_t)i * 2;
  float4 a = s[0], b = s[1];
  uint4 o;
  o.x = pk2(a.x, a.y); o.y = pk2(a.z, a.w);
  o.z = pk2(b.x, b.y); o.w = pk2(b.z, b.w);
  ((uint4*)dst)[i] = o;
}

// ---- all three weight matrices in one launch --------------------------------
__global__ __launch_bounds__(256) void cvt_weights(
    const float* __restrict__ W, const float* __restrict__ phi,
    const float* __restrict__ pred,
    unsigned short* __restrict__ Wb, unsigned short* __restrict__ phib,
    unsigned short* __restrict__ predb)
{
  int i = blockIdx.x * 256 + threadIdx.x;   // 5120 units of 8 elems
  if (i >= 5120) return;
  const float* s; unsigned short* d; int j;
  if (i < 2048)      { s = W;    d = Wb;    j = i; }
  else if (i < 4096) { s = phi;  d = phib;  j = i - 2048; }
  else               { s = pred; d = predb; j = i - 4096; }
  const float4* sp = (const float4*)s + (size_t)j * 2;
  float4 a = sp[0], b = sp[1];
  uint4 o;
  o.x = pk2(a.x, a.y); o.y = pk2(a.z, a.w);
  o.z = pk2(b.x, b.y); o.w = pk2(b.z, b.w);
  ((uint4*)d)[j] = o;
}

// meta layout (u32): [0..NB) bhist | [512..512+NB) base | [1024..1024+NB) gcur
//                    | [1536] oflw_cnt
__global__ __launch_bounds__(512) void k_zero(unsigned* __restrict__ meta) {
  int t = threadIdx.x;
  if (t < NB) meta[t] = 0;
  if (t == 0) meta[1536] = 0;
}

__global__ __launch_bounds__(512) void k_hist(
    const int* __restrict__ ei, unsigned* __restrict__ meta)
{
  __shared__ unsigned lh[NB];
  const int t = threadIdx.x;
  for (int i = t; i < NB; i += 512) lh[i] = 0;
  __syncthreads();
#pragma unroll
  for (int j = 0; j < 8; j++) {
    int e = blockIdx.x * EPB + j * 512 + t;
    if (e < NE) {
      unsigned tgt = (unsigned)ei[NE + e];
      atomicAdd(&lh[tgt >> 8], 1u);
    }
  }
  __syncthreads();
  for (int i = t; i < NB; i += 512)
    if (lh[i]) atomicAdd(&meta[i], lh[i]);
}

__global__ __launch_bounds__(512) void k_scan(unsigned* __restrict__ meta) {
  __shared__ unsigned sc[512];
  const int t = threadIdx.x;
  unsigned v = (t < NB) ? meta[t] : 0u;
  sc[t] = v;
  for (int off = 1; off < 512; off <<= 1) {
    __syncthreads();
    unsigned w = (t >= off) ? sc[t - off] : 0u;
    __syncthreads();
    sc[t] += w;
  }
  unsigned excl = sc[t] - v;
  if (t < NB) { meta[512 + t] = excl; meta[1024 + t] = excl; }
}

// Partition edges into bucket-contiguous runs with coalesced writes.
__global__ __launch_bounds__(512) void k_part(
    const int* __restrict__ ei, unsigned* __restrict__ meta,
    unsigned* __restrict__ edge_part)
{
  __shared__ unsigned lh[512], sc[512], lb[512], gb[512], lcur[512];
  __shared__ unsigned staged[EPB], sgo[EPB];
  __shared__ unsigned tot;
  const int t = threadIdx.x;
  lh[t] = 0;
  __syncthreads();

  unsigned rec[8]; short bb[8];
#pragma unroll
  for (int j = 0; j < 8; j++) {
    int e = blockIdx.x * EPB + j * 512 + t;
    if (e < NE) {
      unsigned tgt = (unsigned)ei[NE + e];
      unsigned src = (unsigned)ei[e];
      unsigned b = tgt >> 8;
      rec[j] = ((tgt & 255u) << 17) | src;
      bb[j] = (short)b;
      atomicAdd(&lh[b], 1u);
    } else bb[j] = -1;
  }
  __syncthreads();

  unsigned v = lh[t];
  sc[t] = v;
  for (int off = 1; off < 512; off <<= 1) {
    __syncthreads();
    unsigned w = (t >= off) ? sc[t - off] : 0u;
    __syncthreads();
    sc[t] += w;
  }
  lb[t] = sc[t] - v;
  lcur[t] = lb[t];
  if (t == 511) tot = sc[511];
  gb[t] = (t < NB && v) ? atomicAdd(&meta[1024 + t], v) : 0u;
  __syncthreads();

#pragma unroll
  for (int j = 0; j < 8; j++) {
    if (bb[j] >= 0) {
      unsigned b = (unsigned)bb[j];
      unsigned o = atomicAdd(&lcur[b], 1u);
      staged[o] = rec[j];
      sgo[o] = gb[b] + (o - lb[b]);
    }
  }
  __syncthreads();
  unsigned T = tot;
#pragma unroll
  for (int j = 0; j < 8; j++) {
    unsigned idx = j * 512 + t;
    if (idx < T) edge_part[sgo[idx]] = staged[idx];
  }
}

// One block per bucket: bin edges into per-node LDS lists, then gather x rows.
__global__ __launch_bounds__(512) void k_gather(
    const unsigned* __restrict__ edge_part, const unsigned* __restrict__ meta,
    const unsigned* __restrict__ xbu,       // xb viewed as u32 (2 bf16 each)
    unsigned* __restrict__ aggbu,           // [NN][64] u32 (bf16 pairs)
    float* __restrict__ degf,
    unsigned* __restrict__ oflw, unsigned* __restrict__ meta_oflw)
{
  __shared__ unsigned cnt[256];
  __shared__ unsigned list[256 * CAP];      // 64 KB
  const int t = threadIdx.x;
  const unsigned b = blockIdx.x;
  const unsigned nbase = b << 8;
  const unsigned ebase = meta[512 + b];
  const unsigned ecnt  = meta[b];
  if (t < 256) cnt[t] = 0;
  __syncthreads();

  for (unsigned k = t; k < ecnt; k += 512) {
    unsigned rec = edge_part[ebase + k];
    unsigned tl = rec >> 17;
    unsigned src = rec & 0x1FFFFu;
    unsigned p = atomicAdd(&cnt[tl], 1u);
    if (p < CAP) list[tl * CAP + p] = src;
    else {
      unsigned op = atomicAdd(&meta_oflw[1536], 1u);
      oflw[op * 2] = nbase + tl;
      oflw[op * 2 + 1] = src;
    }
  }
  __syncthreads();

  const int wave = t >> 6, lane = t & 63;
  for (int k = 0; k < 32; k++) {
    unsigned tl = wave * 32 + k;
    long n = (long)nbase + tl;
    if (n >= NN) continue;
    unsigned deg = cnt[tl];
    if (lane == 0) degf[n] = (float)deg;
    int d2 = deg < CAP ? (int)deg : CAP;
    int my = (lane < d2) ? (int)list[tl * CAP + lane] : 0;
    float ax = 0.f, ay = 0.f;
    int e = 0;
    for (; e + 2 <= d2; e += 2) {
      int s0 = __shfl(my, e, 64);
      int s1 = __shfl(my, e + 1, 64);
      unsigned h0 = xbu[(size_t)s0 * 64 + lane];
      unsigned h1 = xbu[(size_t)s1 * 64 + lane];
      ax += blo(h0); ay += bhi(h0);
      ax += blo(h1); ay += bhi(h1);
    }
    if (e < d2) {
      int s0 = __shfl(my, e, 64);
      unsigned h0 = xbu[(size_t)s0 * 64 + lane];
      ax += blo(h0); ay += bhi(h0);
    }
    aggbu[n * 64 + lane] = pk2(ax, ay);
  }
}

// Serial fix-up for deg>CAP spill edges (normally zero iterations).
__global__ __launch_bounds__(64) void k_oflow(
    const unsigned* __restrict__ meta, const unsigned* __restrict__ oflw,
    const float* __restrict__ x, unsigned* __restrict__ aggbu)
{
  const int t = threadIdx.x;
  unsigned m = meta[1536];
  for (unsigned i = 0; i < m; i++) {
    unsigned tgt = oflw[i * 2], src = oflw[i * 2 + 1];
    unsigned c = aggbu[(size_t)tgt * 64 + t];
    float a0 = blo(c) + x[(size_t)src * HD + t * 2];
    float a1 = bhi(c) + x[(size_t)src * HD + t * 2 + 1];
    aggbu[(size_t)tgt * 64 + t] = pk2(a0, a1);
  }
}

// Fused K=256 GEMM: x_new = relu(W@agg + deg*W_b + phi@u + phi_b), then
// pred head y = x_new @ pred^T + pred_b via swizzled LDS stage. 128 nodes/blk.
__global__ __launch_bounds__(256) void k_fused(
    const unsigned* __restrict__ aggbu,
    const float* __restrict__ u,
    const float* __restrict__ degf,
    const unsigned short* __restrict__ Wb,
    const unsigned short* __restrict__ phib,
    const unsigned short* __restrict__ predb,
    const float* __restrict__ W_b, const float* __restrict__ phi_b,
    const float* __restrict__ pred_b,
    float* __restrict__ out_x, float* __restrict__ out_y)
{
  __shared__ unsigned xs[4 * 32 * 64];      // 32 KB: per-wave x_new bf16, swizzled
  const int lane = threadIdx.x & 63;
  const int wv   = threadIdx.x >> 6;
  const long n0  = (long)blockIdx.x * 128 + wv * 32;
  const int r = lane & 15, h4 = lane >> 4;

  U8 xf[2][4], uf[2][4];
  float dg[2];
#pragma unroll
  for (int nt = 0; nt < 2; nt++) {
    long n = n0 + nt * 16 + r;
    long nc = (n < NN) ? n : 0;
    dg[nt] = degf[nc];
    const unsigned* arow = aggbu + nc * 64 + h4 * 4;
    const float* urow = u + nc * HD + h4 * 8;
#pragma unroll
    for (int ks = 0; ks < 4; ks++) {
      xf[nt][ks].u = *(const uint4*)(arow + ks * 16);
      float4 a = *(const float4*)(urow + ks * 32);
      float4 b = *(const float4*)(urow + ks * 32 + 4);
      uf[nt][ks].u = make_uint4(pk2(a.x, a.y), pk2(a.z, a.w),
                                pk2(b.x, b.y), pk2(b.z, b.w));
    }
  }

#pragma unroll
  for (int ct = 0; ct < 8; ct++) {
    const int c0 = ct * 16 + r;
    float4 wb4 = *(const float4*)&W_b[ct * 16 + h4 * 4];
    float4 pb4 = *(const float4*)&phi_b[ct * 16 + h4 * 4];
    v4f acc[2];
#pragma unroll
    for (int nt = 0; nt < 2; nt++)
      acc[nt] = (v4f){fmaf(dg[nt], wb4.x, pb4.x), fmaf(dg[nt], wb4.y, pb4.y),
                      fmaf(dg[nt], wb4.z, pb4.z), fmaf(dg[nt], wb4.w, pb4.w)};
#pragma unroll
    for (int ks = 0; ks < 4; ks++) {
      short8 wf = *(const short8*)&Wb[(size_t)c0 * HD + ks * 32 + h4 * 8];
      acc[0] = __builtin_amdgcn_mfma_f32_16x16x32_bf16(wf, xf[0][ks].s, acc[0], 0, 0, 0);
      acc[1] = __builtin_amdgcn_mfma_f32_16x16x32_bf16(wf, xf[1][ks].s, acc[1], 0, 0, 0);
    }
#pragma unroll
    for (int ks = 0; ks < 4; ks++) {
      short8 pf = *(const short8*)&phib[(size_t)c0 * HD + ks * 32 + h4 * 8];
      acc[0] = __builtin_amdgcn_mfma_f32_16x16x32_bf16(pf, uf[0][ks].s, acc[0], 0, 0, 0);
      acc[1] = __builtin_amdgcn_mfma_f32_16x16x32_bf16(pf, uf[1][ks].s, acc[1], 0, 0, 0);
    }
#pragma unroll
    for (int nt = 0; nt < 2; nt++) {
      float r0 = fmaxf(acc[nt][0], 0.f), r1 = fmaxf(acc[nt][1], 0.f);
      float r2 = fmaxf(acc[nt][2], 0.f), r3 = fmaxf(acc[nt][3], 0.f);
      long n = n0 + nt * 16 + r;
      if (n < NN)
        *(float4*)&out_x[n * HD + ct * 16 + h4 * 4] = make_float4(r0, r1, r2, r3);
      int lr = nt * 16 + r;
      int chunk = ct * 2 + (h4 >> 1);
      unsigned* dst = &xs[(wv * 32 + lr) * 64 + ((chunk ^ r) << 2) + ((h4 & 1) << 1)];
      *(uint2*)dst = make_uint2(pk2(r0, r1), pk2(r2, r3));
    }
  }
  __syncthreads();

#pragma unroll
  for (int ct2 = 0; ct2 < 4; ct2++) {
    float4 qb4 = *(const float4*)&pred_b[ct2 * 16 + h4 * 4];
    v4f acc[2];
    acc[0] = (v4f){qb4.x, qb4.y, qb4.z, qb4.w};
    acc[1] = acc[0];
#pragma unroll
    for (int ks = 0; ks < 4; ks++) {
      short8 pw = *(const short8*)&predb[(size_t)(ct2 * 16 + r) * HD + ks * 32 + h4 * 8];
#pragma unroll
      for (int nt = 0; nt < 2; nt++) {
        U8 bx;
        bx.u = *(const uint4*)&xs[(wv * 32 + nt * 16 + r) * 64 + (((h4 + ks * 4) ^ r) << 2)];
        acc[nt] = __builtin_amdgcn_mfma_f32_16x16x32_bf16(pw, bx.s, acc[nt], 0, 0, 0);
      }
    }
#pragma unroll
    for (int nt = 0; nt < 2; nt++) {
      long n = n0 + nt * 16 + r;
      if (n < NN)
        *(float4*)&out_y[n * 64 + ct2 * 16 + h4 * 4] =
            make_float4(acc[nt][0], acc[nt][1], acc[nt][2], acc[nt][3]);
    }
  }
}

// ---- fp32 fallback path (only if ws is too small) ---------------------------
template<int CT, int LDO, bool RELU_WB>
__global__ __launch_bounds__(256) void gemm_nodes(
    const float* __restrict__ in, float* in_wb,
    const float* __restrict__ Wg, const float* __restrict__ bias,
    float* __restrict__ out)
{
  __shared__ float Wt[HD * CT];
  __shared__ float xsh[32 * HD];
  const int tid = threadIdx.x;
  const int cbase = blockIdx.y * CT;
  for (int idx = tid; idx < HD * CT; idx += 256) {
    int c = idx >> 7, k = idx & 127;
    int chunk = ((c >> 1) ^ (k & 31));
    Wt[k * CT + (chunk << 1 | (c & 1))] = Wg[(size_t)(cbase + c) * HD + k];
  }
  const long nb = (long)blockIdx.x * 32;
  for (int idx = tid; idx < 32 * HD; idx += 256) {
    int n = idx >> 7, k = idx & 127;
    float v = in[(nb + n) * HD + k];
    if (RELU_WB) { v = fmaxf(v, 0.0f); in_wb[(nb + n) * HD + k] = v; }
    xsh[idx] = v;
  }
  __syncthreads();
  const int lane = tid & 31, grp = tid >> 5, c0 = lane * 2;
  float acc[4][2];
#pragma unroll
  for (int j = 0; j < 4; j++) { acc[j][0] = bias[cbase + c0]; acc[j][1] = bias[cbase + c0 + 1]; }
#pragma unroll 4
  for (int k = 0; k < HD; k += 4) {
    float xv[4][4];
#pragma unroll
    for (int j = 0; j < 4; j++) {
      float4 t = *(const float4*)&xsh[(grp * 4 + j) * HD + k];
      xv[j][0] = t.x; xv[j][1] = t.y; xv[j][2] = t.z; xv[j][3] = t.w;
    }
#pragma unroll
    for (int kk = 0; kk < 4; kk++) {
      int chunk = lane ^ ((k + kk) & 31);
      float2 w = *(const float2*)&Wt[(k + kk) * CT + (chunk << 1)];
#pragma unroll
      for (int j = 0; j < 4; j++) {
        acc[j][0] = fmaf(xv[j][kk], w.x, acc[j][0]);
        acc[j][1] = fmaf(xv[j][kk], w.y, acc[j][1]);
      }
    }
  }
#pragma unroll
  for (int j = 0; j < 4; j++) {
    long n = nb + grp * 4 + j;
    *(float2*)&out[n * LDO + c0 + cbase] = make_float2(acc[j][0], acc[j][1]);
  }
}

__global__ __launch_bounds__(256) void scatter_edges(
    const int* __restrict__ ei, const float* __restrict__ h, float* __restrict__ agg)
{
  const long t = (long)blockIdx.x * 256 + threadIdx.x;
  const int e = (int)(t >> 5), lane = (int)(t & 31);
  const int src = ei[e], tgt = ei[NE + e];
  const float4 v = *(const float4*)&h[(size_t)src * HD + lane * 4];
  float* dst = &agg[(size_t)tgt * HD + lane * 4];
  unsafeAtomicAdd(dst + 0, v.x); unsafeAtomicAdd(dst + 1, v.y);
  unsafeAtomicAdd(dst + 2, v.z); unsafeAtomicAdd(dst + 3, v.w);
}

// ---- launch -----------------------------------------------------------------
extern "C" void kernel_launch(void* const* d_in, const int* in_sizes, int n_in,
                              void* d_out, int out_size, void* d_ws, size_t ws_size,
                              hipStream_t stream) {
  const float* x      = (const float*)d_in[0];
  const float* u      = (const float*)d_in[1];
  const int*   ei     = (const int*)d_in[2];
  const float* W_w    = (const float*)d_in[3];
  const float* W_b    = (const float*)d_in[4];
  const float* phi_w  = (const float*)d_in[5];
  const float* phi_b  = (const float*)d_in[6];
  const float* pred_w = (const float*)d_in[7];
  const float* pred_b = (const float*)d_in[8];

  float* out_x = (float*)d_out;                       // [NN,128] x_new (f32)
  float* out_y = (float*)d_out + (size_t)NN * HD;     // [NN,64]  y (f32)

  // workspace layout (all 256B-aligned)
  char* p = (char*)d_ws;
  auto take = [&](size_t bytes) { char* r = p; p += (bytes + 255) & ~(size_t)255; return r; };
  unsigned short* xb  = (unsigned short*)take((size_t)NN * HD * 2);   // 25.6 MB
  unsigned* aggbu     = (unsigned*)take((size_t)NN * 64 * 4);         // 25.6 MB
  unsigned* edge_part = (unsigned*)take((size_t)NE * 4);              // 6.4 MB
  unsigned* oflw      = (unsigned*)take((size_t)NE * 8);              // 12.8 MB
  float* degf         = (float*)take((size_t)NN * 4);                 // 0.4 MB
  unsigned short* Wb    = (unsigned short*)take(16384 * 2);
  unsigned short* phib  = (unsigned short*)take(16384 * 2);
  unsigned short* predb = (unsigned short*)take(8192 * 2);
  unsigned* meta      = (unsigned*)take(2048 * 4);
  const size_t need = (size_t)(p - (char*)d_ws);

  dim3 b256(256), b512(512);
  if (ws_size >= need) {
    const int n8x = NN * HD / 8;                      // 1.6M
    cvt_bf16<<<dim3((n8x + 255) / 256), b256, 0, stream>>>(x, xb, n8x);
    cvt_weights<<<dim3(20), b256, 0, stream>>>(W_w, phi_w, pred_w, Wb, phib, predb);
    k_zero<<<dim3(1), b512, 0, stream>>>(meta);
    k_hist<<<dim3((NE + EPB - 1) / EPB), b512, 0, stream>>>(ei, meta);
    k_scan<<<dim3(1), b512, 0, stream>>>(meta);
    k_part<<<dim3((NE + EPB - 1) / EPB), b512, 0, stream>>>(ei, meta, edge_part);
    k_gather<<<dim3(NB), b512, 0, stream>>>(edge_part, meta, (const unsigned*)xb,
                                            aggbu, degf, oflw, meta);
    k_oflow<<<dim3(1), dim3(64), 0, stream>>>(meta, oflw, x, aggbu);
    k_fused<<<dim3((NN + 127) / 128), b256, 0, stream>>>(
        aggbu, u, degf, Wb, phib, predb, W_b, phi_b, pred_b, out_x, out_y);
  } else {
    float* h = (float*)d_ws;
    gemm_nodes<64, 128, false><<<dim3(NN / 32, 2), b256, 0, stream>>>(x, nullptr, W_w, W_b, h);
    gemm_nodes<64, 128, false><<<dim3(NN / 32, 2), b256, 0, stream>>>(u, nullptr, phi_w, phi_b, out_x);
    scatter_edges<<<dim3((NE * 32) / 256), b256, 0, stream>>>(ei, h, out_x);
    gemm_nodes<64, 64, true><<<dim3(NN / 32, 1), b256, 0, stream>>>(out_x, out_x, pred_w, pred_b, out_y);
  }
}

// Round 6
// 318.759 us; speedup vs baseline: 9.4319x; 1.1778x over previous
//
#include <hip/hip_runtime.h>

#define NN 100000
#define NE 1600000
#define HD 128
#define NB 391          // coarse buckets of 256 target nodes (tgt>>8)
#define QN 64           // nodes per gather block (quarter bucket)
#define CAP 64          // per-node LDS list capacity; deg~Poisson(16)
#define EPB 4096        // edges per histogram/partition block

typedef __attribute__((ext_vector_type(8))) short short8;   // 8 bf16
typedef __attribute__((ext_vector_type(4))) float v4f;
union U8 { uint4 u; short8 s; };

__device__ inline unsigned pk2(float a, float b) {          // 2x f32 -> packed bf16 (RNE)
  unsigned ua = __float_as_uint(a), ub = __float_as_uint(b);
  ua = (ua + 0x7fffu + ((ua >> 16) & 1u)) >> 16;
  ub = (ub + 0x7fffu + ((ub >> 16) & 1u)) >> 16;
  return ua | (ub << 16);
}
__device__ inline float blo(unsigned h) { return __uint_as_float(h << 16); }
__device__ inline float bhi(unsigned h) { return __uint_as_float(h & 0xffff0000u); }

// ---- fp32 -> bf16 bulk convert (8 elems/thread) -----------------------------
__global__ __launch_bounds__(256) void cvt_bf16(
    const float* __restrict__ src, unsigned short* __restrict__ dst, int n8)
{
  int i = blockIdx.x * 256 + threadIdx.x;
  if (i >= n8) return;
  const float4* s = (const float4*)src + (size_t)i * 2;
  float4 a = s[0], b = s[1];
  uint4 o;
  o.x = pk2(a.x, a.y); o.y = pk2(a.z, a.w);
  o.z = pk2(b.x, b.y); o.w = pk2(b.z, b.w);
  ((uint4*)dst)[i] = o;
}

// ---- weights cvt + meta zero in one launch (grid 21) ------------------------
__global__ __launch_bounds__(256) void cvt_weights(
    const float* __restrict__ W, const float* __restrict__ phi,
    const float* __restrict__ pred,
    unsigned short* __restrict__ Wb, unsigned short* __restrict__ phib,
    unsigned short* __restrict__ predb, unsigned* __restrict__ meta)
{
  if (blockIdx.x == 20) {                   // meta zero block
    for (int j = threadIdx.x; j < NB; j += 256) meta[j] = 0;
    if (threadIdx.x == 0) meta[1536] = 0;
    return;
  }
  int i = blockIdx.x * 256 + threadIdx.x;   // 5120 units of 8 elems
  const float* s; unsigned short* d; int j;
  if (i < 2048)      { s = W;    d = Wb;    j = i; }
  else if (i < 4096) { s = phi;  d = phib;  j = i - 2048; }
  else               { s = pred; d = predb; j = i - 4096; }
  const float4* sp = (const float4*)s + (size_t)j * 2;
  float4 a = sp[0], b = sp[1];
  uint4 o;
  o.x = pk2(a.x, a.y); o.y = pk2(a.z, a.w);
  o.z = pk2(b.x, b.y); o.w = pk2(b.z, b.w);
  ((uint4*)d)[j] = o;
}

// meta layout (u32): [0..NB) bhist | [512..512+NB) base | [1024..1024+NB) gcur
//                    | [1536] oflw_cnt
__global__ __launch_bounds__(512) void k_hist(
    const int* __restrict__ ei, unsigned* __restrict__ meta)
{
  __shared__ unsigned lh[NB];
  const int t = threadIdx.x;
  for (int i = t; i < NB; i += 512) lh[i] = 0;
  __syncthreads();
#pragma unroll
  for (int j = 0; j < 8; j++) {
    int e = blockIdx.x * EPB + j * 512 + t;
    if (e < NE) {
      unsigned tgt = (unsigned)ei[NE + e];
      atomicAdd(&lh[tgt >> 8], 1u);
    }
  }
  __syncthreads();
  for (int i = t; i < NB; i += 512)
    if (lh[i]) atomicAdd(&meta[i], lh[i]);
}

__global__ __launch_bounds__(512) void k_scan(unsigned* __restrict__ meta) {
  __shared__ unsigned sc[512];
  const int t = threadIdx.x;
  unsigned v = (t < NB) ? meta[t] : 0u;
  sc[t] = v;
  for (int off = 1; off < 512; off <<= 1) {
    __syncthreads();
    unsigned w = (t >= off) ? sc[t - off] : 0u;
    __syncthreads();
    sc[t] += w;
  }
  unsigned excl = sc[t] - v;
  if (t < NB) { meta[512 + t] = excl; meta[1024 + t] = excl; }
}

// Partition edges into bucket-contiguous runs with coalesced writes.
__global__ __launch_bounds__(512) void k_part(
    const int* __restrict__ ei, unsigned* __restrict__ meta,
    unsigned* __restrict__ edge_part)
{
  __shared__ unsigned lh[512], sc[512], lb[512], gb[512], lcur[512];
  __shared__ unsigned staged[EPB], sgo[EPB];
  __shared__ unsigned tot;
  const int t = threadIdx.x;
  lh[t] = 0;
  __syncthreads();

  unsigned rec[8]; short bb[8];
#pragma unroll
  for (int j = 0; j < 8; j++) {
    int e = blockIdx.x * EPB + j * 512 + t;
    if (e < NE) {
      unsigned tgt = (unsigned)ei[NE + e];
      unsigned src = (unsigned)ei[e];
      unsigned b = tgt >> 8;
      rec[j] = ((tgt & 255u) << 17) | src;
      bb[j] = (short)b;
      atomicAdd(&lh[b], 1u);
    } else bb[j] = -1;
  }
  __syncthreads();

  unsigned v = lh[t];
  sc[t] = v;
  for (int off = 1; off < 512; off <<= 1) {
    __syncthreads();
    unsigned w = (t >= off) ? sc[t - off] : 0u;
    __syncthreads();
    sc[t] += w;
  }
  lb[t] = sc[t] - v;
  lcur[t] = lb[t];
  if (t == 511) tot = sc[511];
  gb[t] = (t < NB && v) ? atomicAdd(&meta[1024 + t], v) : 0u;
  __syncthreads();

#pragma unroll
  for (int j = 0; j < 8; j++) {
    if (bb[j] >= 0) {
      unsigned b = (unsigned)bb[j];
      unsigned o = atomicAdd(&lcur[b], 1u);
      staged[o] = rec[j];
      sgo[o] = gb[b] + (o - lb[b]);
    }
  }
  __syncthreads();
  unsigned T = tot;
#pragma unroll
  for (int j = 0; j < 8; j++) {
    unsigned idx = j * 512 + t;
    if (idx < T) edge_part[sgo[idx]] = staged[idx];
  }
}

// One block per QUARTER bucket (64 nodes): bin this quarter's edges into
// per-node LDS lists, then gather x rows with 16-lane uint4 groups.
__global__ __launch_bounds__(512) void k_gather(
    const unsigned* __restrict__ edge_part, const unsigned* __restrict__ meta,
    const uint4* __restrict__ xb4,          // xb as uint4 (16 B = 8 bf16)
    unsigned* __restrict__ aggbu,           // [NN][64] u32 (bf16 pairs)
    float* __restrict__ degf,
    unsigned* __restrict__ oflw, unsigned* __restrict__ meta_oflw)
{
  __shared__ unsigned cnt[QN];
  __shared__ unsigned list[QN * CAP];       // 16 KB
  const int t = threadIdx.x;
  const unsigned b = blockIdx.x >> 2;       // coarse bucket
  const unsigned q = blockIdx.x & 3;        // quarter within bucket
  const unsigned nbase = (b << 8) + (q << 6);
  const unsigned ebase = meta[512 + b];
  const unsigned ecnt  = meta[b];
  if (t < QN) cnt[t] = 0;
  __syncthreads();

  for (unsigned k = t; k < ecnt; k += 512) {
    unsigned rec = edge_part[ebase + k];
    unsigned tl = rec >> 17;
    if ((tl >> 6) == q) {
      unsigned ql = tl & 63;
      unsigned src = rec & 0x1FFFFu;
      unsigned p = atomicAdd(&cnt[ql], 1u);
      if (p < CAP) list[ql * CAP + p] = src;
      else {
        unsigned op = atomicAdd(&meta_oflw[1536], 1u);
        oflw[op * 2] = nbase + ql;
        oflw[op * 2 + 1] = src;
      }
    }
  }
  __syncthreads();

  const int wave = t >> 6, lane = t & 63;
  const int g = lane >> 4, c = lane & 15;   // 4 edge-slots x 16 channel-quads
#pragma unroll
  for (int k = 0; k < 8; k++) {
    unsigned ql = wave * 8 + k;
    long n = (long)nbase + ql;
    if (n >= NN) continue;
    unsigned deg = cnt[ql];
    if (lane == 0) degf[n] = (float)deg;
    int d2 = deg < CAP ? (int)deg : CAP;
    float a[8] = {0, 0, 0, 0, 0, 0, 0, 0};
    for (int e = g; e < d2; e += 4) {        // 4 edges in flight per wave
      unsigned s = list[ql * CAP + e];       // broadcast within 16-lane group
      uint4 v = xb4[(size_t)s * 16 + c];     // 256 B contiguous per group
      a[0] += blo(v.x); a[1] += bhi(v.x);
      a[2] += blo(v.y); a[3] += bhi(v.y);
      a[4] += blo(v.z); a[5] += bhi(v.z);
      a[6] += blo(v.w); a[7] += bhi(v.w);
    }
#pragma unroll
    for (int m = 16; m <= 32; m <<= 1)
#pragma unroll
      for (int j = 0; j < 8; j++)
        a[j] += __shfl_xor(a[j], m, 64);
    if (g == 0) {
      uint4 o = make_uint4(pk2(a[0], a[1]), pk2(a[2], a[3]),
                           pk2(a[4], a[5]), pk2(a[6], a[7]));
      *(uint4*)&aggbu[n * 64 + c * 4] = o;
    }
  }
}

// Serial fix-up for deg>CAP spill edges (normally zero iterations).
__global__ __launch_bounds__(64) void k_oflow(
    const unsigned* __restrict__ meta, const unsigned* __restrict__ oflw,
    const float* __restrict__ x, unsigned* __restrict__ aggbu)
{
  const int t = threadIdx.x;
  unsigned m = meta[1536];
  for (unsigned i = 0; i < m; i++) {
    unsigned tgt = oflw[i * 2], src = oflw[i * 2 + 1];
    unsigned c = aggbu[(size_t)tgt * 64 + t];
    float a0 = blo(c) + x[(size_t)src * HD + t * 2];
    float a1 = bhi(c) + x[(size_t)src * HD + t * 2 + 1];
    aggbu[(size_t)tgt * 64 + t] = pk2(a0, a1);
  }
}

// Fused K=256 GEMM: x_new = relu(W@agg + deg*W_b + phi@u + phi_b), then
// pred head y = x_new @ pred^T + pred_b via swizzled LDS stage. 128 nodes/blk.
__global__ __launch_bounds__(256) void k_fused(
    const unsigned* __restrict__ aggbu,
    const float* __restrict__ u,
    const float* __restrict__ degf,
    const unsigned short* __restrict__ Wb,
    const unsigned short* __restrict__ phib,
    const unsigned short* __restrict__ predb,
    const float* __restrict__ W_b, const float* __restrict__ phi_b,
    const float* __restrict__ pred_b,
    float* __restrict__ out_x, float* __restrict__ out_y)
{
  __shared__ unsigned xs[4 * 32 * 64];      // 32 KB: per-wave x_new bf16, swizzled
  const int lane = threadIdx.x & 63;
  const int wv   = threadIdx.x >> 6;
  const long n0  = (long)blockIdx.x * 128 + wv * 32;
  const int r = lane & 15, h4 = lane >> 4;

  U8 xf[2][4], uf[2][4];
  float dg[2];
#pragma unroll
  for (int nt = 0; nt < 2; nt++) {
    long n = n0 + nt * 16 + r;
    long nc = (n < NN) ? n : 0;
    dg[nt] = degf[nc];
    const unsigned* arow = aggbu + nc * 64 + h4 * 4;
    const float* urow = u + nc * HD + h4 * 8;
#pragma unroll
    for (int ks = 0; ks < 4; ks++) {
      xf[nt][ks].u = *(const uint4*)(arow + ks * 16);
      float4 a = *(const float4*)(urow + ks * 32);
      float4 b = *(const float4*)(urow + ks * 32 + 4);
      uf[nt][ks].u = make_uint4(pk2(a.x, a.y), pk2(a.z, a.w),
                                pk2(b.x, b.y), pk2(b.z, b.w));
    }
  }

#pragma unroll
  for (int ct = 0; ct < 8; ct++) {
    const int c0 = ct * 16 + r;
    float4 wb4 = *(const float4*)&W_b[ct * 16 + h4 * 4];
    float4 pb4 = *(const float4*)&phi_b[ct * 16 + h4 * 4];
    v4f acc[2];
#pragma unroll
    for (int nt = 0; nt < 2; nt++)
      acc[nt] = (v4f){fmaf(dg[nt], wb4.x, pb4.x), fmaf(dg[nt], wb4.y, pb4.y),
                      fmaf(dg[nt], wb4.z, pb4.z), fmaf(dg[nt], wb4.w, pb4.w)};
#pragma unroll
    for (int ks = 0; ks < 4; ks++) {
      short8 wf = *(const short8*)&Wb[(size_t)c0 * HD + ks * 32 + h4 * 8];
      acc[0] = __builtin_amdgcn_mfma_f32_16x16x32_bf16(wf, xf[0][ks].s, acc[0], 0, 0, 0);
      acc[1] = __builtin_amdgcn_mfma_f32_16x16x32_bf16(wf, xf[1][ks].s, acc[1], 0, 0, 0);
    }
#pragma unroll
    for (int ks = 0; ks < 4; ks++) {
      short8 pf = *(const short8*)&phib[(size_t)c0 * HD + ks * 32 + h4 * 8];
      acc[0] = __builtin_amdgcn_mfma_f32_16x16x32_bf16(pf, uf[0][ks].s, acc[0], 0, 0, 0);
      acc[1] = __builtin_amdgcn_mfma_f32_16x16x32_bf16(pf, uf[1][ks].s, acc[1], 0, 0, 0);
    }
#pragma unroll
    for (int nt = 0; nt < 2; nt++) {
      float r0 = fmaxf(acc[nt][0], 0.f), r1 = fmaxf(acc[nt][1], 0.f);
      float r2 = fmaxf(acc[nt][2], 0.f), r3 = fmaxf(acc[nt][3], 0.f);
      long n = n0 + nt * 16 + r;
      if (n < NN)
        *(float4*)&out_x[n * HD + ct * 16 + h4 * 4] = make_float4(r0, r1, r2, r3);
      int lr = nt * 16 + r;
      int chunk = ct * 2 + (h4 >> 1);
      unsigned* dst = &xs[(wv * 32 + lr) * 64 + ((chunk ^ r) << 2) + ((h4 & 1) << 1)];
      *(uint2*)dst = make_uint2(pk2(r0, r1), pk2(r2, r3));
    }
  }
  __syncthreads();

#pragma unroll
  for (int ct2 = 0; ct2 < 4; ct2++) {
    float4 qb4 = *(const float4*)&pred_b[ct2 * 16 + h4 * 4];
    v4f acc[2];
    acc[0] = (v4f){qb4.x, qb4.y, qb4.z, qb4.w};
    acc[1] = acc[0];
#pragma unroll
    for (int ks = 0; ks < 4; ks++) {
      short8 pw = *(const short8*)&predb[(size_t)(ct2 * 16 + r) * HD + ks * 32 + h4 * 8];
#pragma unroll
      for (int nt = 0; nt < 2; nt++) {
        U8 bx;
        bx.u = *(const uint4*)&xs[(wv * 32 + nt * 16 + r) * 64 + (((h4 + ks * 4) ^ r) << 2)];
        acc[nt] = __builtin_amdgcn_mfma_f32_16x16x32_bf16(pw, bx.s, acc[nt], 0, 0, 0);
      }
    }
#pragma unroll
    for (int nt = 0; nt < 2; nt++) {
      long n = n0 + nt * 16 + r;
      if (n < NN)
        *(float4*)&out_y[n * 64 + ct2 * 16 + h4 * 4] =
            make_float4(acc[nt][0], acc[nt][1], acc[nt][2], acc[nt][3]);
    }
  }
}

// ---- fp32 fallback path (only if ws is too small) ---------------------------
template<int CT, int LDO, bool RELU_WB>
__global__ __launch_bounds__(256) void gemm_nodes(
    const float* __restrict__ in, float* in_wb,
    const float* __restrict__ Wg, const float* __restrict__ bias,
    float* __restrict__ out)
{
  __shared__ float Wt[HD * CT];
  __shared__ float xsh[32 * HD];
  const int tid = threadIdx.x;
  const int cbase = blockIdx.y * CT;
  for (int idx = tid; idx < HD * CT; idx += 256) {
    int c = idx >> 7, k = idx & 127;
    int chunk = ((c >> 1) ^ (k & 31));
    Wt[k * CT + (chunk << 1 | (c & 1))] = Wg[(size_t)(cbase + c) * HD + k];
  }
  const long nb = (long)blockIdx.x * 32;
  for (int idx = tid; idx < 32 * HD; idx += 256) {
    int n = idx >> 7, k = idx & 127;
    float v = in[(nb + n) * HD + k];
    if (RELU_WB) { v = fmaxf(v, 0.0f); in_wb[(nb + n) * HD + k] = v; }
    xsh[idx] = v;
  }
  __syncthreads();
  const int lane = tid & 31, grp = tid >> 5, c0 = lane * 2;
  float acc[4][2];
#pragma unroll
  for (int j = 0; j < 4; j++) { acc[j][0] = bias[cbase + c0]; acc[j][1] = bias[cbase + c0 + 1]; }
#pragma unroll 4
  for (int k = 0; k < HD; k += 4) {
    float xv[4][4];
#pragma unroll
    for (int j = 0; j < 4; j++) {
      float4 t = *(const float4*)&xsh[(grp * 4 + j) * HD + k];
      xv[j][0] = t.x; xv[j][1] = t.y; xv[j][2] = t.z; xv[j][3] = t.w;
    }
#pragma unroll
    for (int kk = 0; kk < 4; kk++) {
      int chunk = lane ^ ((k + kk) & 31);
      float2 w = *(const float2*)&Wt[(k + kk) * CT + (chunk << 1)];
#pragma unroll
      for (int j = 0; j < 4; j++) {
        acc[j][0] = fmaf(xv[j][kk], w.x, acc[j][0]);
        acc[j][1] = fmaf(xv[j][kk], w.y, acc[j][1]);
      }
    }
  }
#pragma unroll
  for (int j = 0; j < 4; j++) {
    long n = nb + grp * 4 + j;
    *(float2*)&out[n * LDO + c0 + cbase] = make_float2(acc[j][0], acc[j][1]);
  }
}

__global__ __launch_bounds__(256) void scatter_edges(
    const int* __restrict__ ei, const float* __restrict__ h, float* __restrict__ agg)
{
  const long t = (long)blockIdx.x * 256 + threadIdx.x;
  const int e = (int)(t >> 5), lane = (int)(t & 31);
  const int src = ei[e], tgt = ei[NE + e];
  const float4 v = *(const float4*)&h[(size_t)src * HD + lane * 4];
  float* dst = &agg[(size_t)tgt * HD + lane * 4];
  unsafeAtomicAdd(dst + 0, v.x); unsafeAtomicAdd(dst + 1, v.y);
  unsafeAtomicAdd(dst + 2, v.z); unsafeAtomicAdd(dst + 3, v.w);
}

// ---- launch -----------------------------------------------------------------
extern "C" void kernel_launch(void* const* d_in, const int* in_sizes, int n_in,
                              void* d_out, int out_size, void* d_ws, size_t ws_size,
                              hipStream_t stream) {
  const float* x      = (const float*)d_in[0];
  const float* u      = (const float*)d_in[1];
  const int*   ei     = (const int*)d_in[2];
  const float* W_w    = (const float*)d_in[3];
  const float* W_b    = (const float*)d_in[4];
  const float* phi_w  = (const float*)d_in[5];
  const float* phi_b  = (const float*)d_in[6];
  const float* pred_w = (const float*)d_in[7];
  const float* pred_b = (const float*)d_in[8];

  float* out_x = (float*)d_out;                       // [NN,128] x_new (f32)
  float* out_y = (float*)d_out + (size_t)NN * HD;     // [NN,64]  y (f32)

  // workspace layout (all 256B-aligned)
  char* p = (char*)d_ws;
  auto take = [&](size_t bytes) { char* r = p; p += (bytes + 255) & ~(size_t)255; return r; };
  unsigned short* xb  = (unsigned short*)take((size_t)NN * HD * 2);   // 25.6 MB
  unsigned* aggbu     = (unsigned*)take((size_t)NN * 64 * 4);         // 25.6 MB
  unsigned* edge_part = (unsigned*)take((size_t)NE * 4);              // 6.4 MB
  unsigned* oflw      = (unsigned*)take((size_t)NE * 8);              // 12.8 MB
  float* degf         = (float*)take((size_t)NN * 4);                 // 0.4 MB
  unsigned short* Wb    = (unsigned short*)take(16384 * 2);
  unsigned short* phib  = (unsigned short*)take(16384 * 2);
  unsigned short* predb = (unsigned short*)take(8192 * 2);
  unsigned* meta      = (unsigned*)take(2048 * 4);
  const size_t need = (size_t)(p - (char*)d_ws);

  dim3 b256(256), b512(512);
  if (ws_size >= need) {
    const int n8x = NN * HD / 8;                      // 1.6M
    cvt_bf16<<<dim3((n8x + 255) / 256), b256, 0, stream>>>(x, xb, n8x);
    cvt_weights<<<dim3(21), b256, 0, stream>>>(W_w, phi_w, pred_w, Wb, phib, predb, meta);
    k_hist<<<dim3((NE + EPB - 1) / EPB), b512, 0, stream>>>(ei, meta);
    k_scan<<<dim3(1), b512, 0, stream>>>(meta);
    k_part<<<dim3((NE + EPB - 1) / EPB), b512, 0, stream>>>(ei, meta, edge_part);
    k_gather<<<dim3(NB * 4), b512, 0, stream>>>(edge_part, meta, (const uint4*)xb,
                                                aggbu, degf, oflw, meta);
    k_oflow<<<dim3(1), dim3(64), 0, stream>>>(meta, oflw, x, aggbu);
    k_fused<<<dim3((NN + 127) / 128), b256, 0, stream>>>(
        aggbu, u, degf, Wb, phib, predb, W_b, phi_b, pred_b, out_x, out_y);
  } else {
    float* h = (float*)d_ws;
    gemm_nodes<64, 128, false><<<dim3(NN / 32, 2), b256, 0, stream>>>(x, nullptr, W_w, W_b, h);
    gemm_nodes<64, 128, false><<<dim3(NN / 32, 2), b256, 0, stream>>>(u, nullptr, phi_w, phi_b, out_x);
    scatter_edges<<<dim3((NE * 32) / 256), b256, 0, stream>>>(ei, h, out_x);
    gemm_nodes<64, 64, true><<<dim3(NN / 32, 1), b256, 0, stream>>>(out_x, out_x, pred_w, pred_b, out_y);
  }
}